// Round 6
// baseline (356.758 us; speedup 1.0000x reference)
//
#include <hip/hip_runtime.h>
#include <math.h>

#define SEQ 2048
#define NHEAD 8
#define HDIM 64
#define BATCH 2

typedef __attribute__((ext_vector_type(8))) short short8;
typedef __attribute__((ext_vector_type(4))) float f32x4;

__device__ __forceinline__ ushort f2bf(float f) {
    union { float f; unsigned u; } v; v.f = f;
    unsigned r = v.u + 0x7FFFu + ((v.u >> 16) & 1u);   // RNE
    return (ushort)(r >> 16);
}

__device__ __forceinline__ f32x4 mfma16(short8 a, short8 b, f32x4 c) {
    return __builtin_amdgcn_mfma_f32_16x16x32_bf16(a, b, c, 0, 0, 0);
}

// ---------------- fused prep: pack x + transpose both weights ------------
__global__ __launch_bounds__(256)
void prep(const float* __restrict__ x, const float* __restrict__ w_qkv,
          const float* __restrict__ w_out, ushort* __restrict__ xb,
          ushort* __restrict__ wqkvT, ushort* __restrict__ woutT)
{
    __shared__ ushort tile[64][66];
    const int blk = blockIdx.x, t = threadIdx.x;
    if (blk < 1024) {                       // pack x -> bf16
        const int i = (blk * 256 + t) * 8;
        float4 a = *(const float4*)&x[i];
        float4 b = *(const float4*)&x[i + 4];
        union { ushort us[8]; uint4 v; } pk;
        pk.us[0] = f2bf(a.x); pk.us[1] = f2bf(a.y); pk.us[2] = f2bf(a.z); pk.us[3] = f2bf(a.w);
        pk.us[4] = f2bf(b.x); pk.us[5] = f2bf(b.y); pk.us[6] = f2bf(b.z); pk.us[7] = f2bf(b.w);
        *(uint4*)&xb[i] = pk.v;
        return;
    }
    const float* w; ushort* wT; int K, N, n0, k0;
    if (blk < 1216) { const int s = blk - 1024; w = w_qkv; wT = wqkvT; K = 512; N = 1536; n0 = (s % 24) * 64; k0 = (s / 24) * 64; }
    else            { const int s = blk - 1216; w = w_out; wT = woutT; K = 512; N = 512;  n0 = (s % 8) * 64;  k0 = (s / 8) * 64; }
#pragma unroll
    for (int i = 0; i < 4; ++i) {
        const int slot = t + i * 256;
        const int r = slot >> 4, c4 = (slot & 15) * 4;
        float4 v = *(const float4*)&w[(size_t)(k0 + r) * N + n0 + c4];
        tile[c4 + 0][r] = f2bf(v.x);
        tile[c4 + 1][r] = f2bf(v.y);
        tile[c4 + 2][r] = f2bf(v.z);
        tile[c4 + 3][r] = f2bf(v.w);
    }
    __syncthreads();
    const int n = t >> 2, kc = (t & 3) * 16;
    union { ushort us[16]; uint4 v[2]; } o;
#pragma unroll
    for (int j = 0; j < 16; ++j) o.us[j] = tile[n][kc + j];
    *(uint4*)&wT[(size_t)(n0 + n) * K + k0 + kc]     = o.v[0];
    *(uint4*)&wT[(size_t)(n0 + n) * K + k0 + kc + 8] = o.v[1];
}

// ------- QKV GEMM: single-wave 32x64 tile, LDS-free, barrier-free --------
__global__ __launch_bounds__(64)
void gemm_qkv_rope(const ushort* __restrict__ xb, const ushort* __restrict__ wT,
                   ushort* __restrict__ qb, ushort* __restrict__ kb,
                   ushort* __restrict__ vtb)
{
    const int lane = threadIdx.x, quad = lane >> 4, l16 = lane & 15;
    const int n0 = blockIdx.x * 64, m0 = blockIdx.y * 32;
    f32x4 acc[2][4] = {};

#pragma unroll 4
    for (int k0 = 0; k0 < 512; k0 += 32) {
        short8 a[2], bfr[4];
#pragma unroll
        for (int i = 0; i < 2; ++i)
            a[i] = *(const short8*)&xb[(size_t)(m0 + i * 16 + l16) * 512 + k0 + quad * 8];
#pragma unroll
        for (int j = 0; j < 4; ++j)
            bfr[j] = *(const short8*)&wT[(size_t)(n0 + j * 16 + l16) * 512 + k0 + quad * 8];
#pragma unroll
        for (int i = 0; i < 2; ++i)
#pragma unroll
            for (int j = 0; j < 4; ++j)
                acc[i][j] = mfma16(a[i], bfr[j], acc[i][j]);
    }

    const int sec = n0 >> 9;   // 0=q 1=k 2=v (uniform per block)
    if (sec == 2) {
#pragma unroll
        for (int i = 0; i < 2; ++i) {
            const int m = m0 + i * 16 + quad * 4;
            const int bidx = m >> 11, n = m & 2047;
#pragma unroll
            for (int j = 0; j < 4; ++j) {
                const int d = j * 16 + l16, h = (n0 >> 6) & 7;
                ushort4 pk;
                pk.x = f2bf(acc[i][j][0]); pk.y = f2bf(acc[i][j][1]);
                pk.z = f2bf(acc[i][j][2]); pk.w = f2bf(acc[i][j][3]);
                *(ushort4*)&vtb[(((size_t)bidx * 8 + h) * 64 + d) * 2048 + n] = pk;
            }
        }
    } else {
        ushort* dst = (sec == 0) ? qb : kb;
        const float scale = (sec == 0) ? 0.125f : 1.0f;
#pragma unroll
        for (int j = 0; j < 4; ++j) {
            const int d = j * 16 + l16, h = (n0 >> 6) & 7;
            const float inv = __expf(-(float)(d & ~1) * (9.2103403719761836f / 64.0f));
#pragma unroll
            for (int i = 0; i < 2; ++i)
#pragma unroll
            for (int r = 0; r < 4; ++r) {
                const int m = m0 + i * 16 + quad * 4 + r;
                const int bidx = m >> 11, n = m & 2047;
                float sn, cs;
                __sincosf((float)n * inv, &sn, &cs);
                const float vacc = acc[i][j][r];
                const float partner = __shfl_xor(vacc, 1);
                const float rot = (d & 1) ? (vacc * cs + partner * sn)
                                          : (vacc * cs - partner * sn);
                dst[(((size_t)bidx * 8 + h) * 2048 + n) * 64 + d] = f2bf(rot * scale);
            }
        }
    }
}

// ------- flash attention: single-wave block, barrier-free, reg ping-pong --
__global__ __launch_bounds__(64)
void flash_attn_wave(const ushort* __restrict__ qb, const ushort* __restrict__ kb,
                     const ushort* __restrict__ vtb, const float* __restrict__ bias,
                     ushort* __restrict__ ob)
{
    __shared__ __align__(16) ushort Ps[16][72];
    const int lane = threadIdx.x, quad = lane >> 4, l16 = lane & 15;
    const int q0 = blockIdx.x * 16, h = blockIdx.y, b = blockIdx.z;
    const size_t bh = (size_t)(b * NHEAD + h);
    const ushort* Q  = qb  + bh * SEQ * HDIM;
    const ushort* Kp = kb  + bh * SEQ * HDIM;
    const ushort* VT = vtb + bh * HDIM * SEQ;

    short8 qf[2];
    qf[0] = *(const short8*)&Q[(size_t)(q0 + l16) * HDIM + quad * 8];
    qf[1] = *(const short8*)&Q[(size_t)(q0 + l16) * HDIM + 32 + quad * 8];

    f32x4 oacc[4] = {};
    float lsum[4] = {};
    const float* bias_base = bias + ((size_t)h * SEQ + q0 + quad * 4) * SEQ;

    // 2-slot register ping-pong (static indices under unroll 2 -> no v_movs)
    short8 kf[2][2][4], vf[2][2][4];
    float bv[2][4][4];
#pragma unroll
    for (int ks = 0; ks < 2; ++ks)
#pragma unroll
        for (int s = 0; s < 4; ++s) {
            kf[0][ks][s] = *(const short8*)&Kp[(size_t)(s * 16 + l16) * HDIM + ks * 32 + quad * 8];
            vf[0][ks][s] = *(const short8*)&VT[(size_t)(s * 16 + l16) * SEQ + ks * 32 + quad * 8];
        }
#pragma unroll
    for (int r = 0; r < 4; ++r)
#pragma unroll
        for (int s = 0; s < 4; ++s)
            bv[0][r][s] = bias_base[(size_t)r * SEQ + s * 16 + l16];

#pragma unroll 2
    for (int it = 0; it < 32; ++it) {
        const int cur = it & 1, nxt = cur ^ 1;
        const int k0 = it * 64;

        // issue next tile's loads first — they stay in flight across the
        // whole compute phase (no barriers anywhere to drain vmcnt)
        if (it < 31) {
#pragma unroll
            for (int ks = 0; ks < 2; ++ks)
#pragma unroll
                for (int s = 0; s < 4; ++s) {
                    kf[nxt][ks][s] = *(const short8*)&Kp[(size_t)(k0 + 64 + s * 16 + l16) * HDIM + ks * 32 + quad * 8];
                    vf[nxt][ks][s] = *(const short8*)&VT[(size_t)(s * 16 + l16) * SEQ + k0 + 64 + ks * 32 + quad * 8];
                }
#pragma unroll
            for (int r = 0; r < 4; ++r)
#pragma unroll
                for (int s = 0; s < 4; ++s)
                    bv[nxt][r][s] = bias_base[(size_t)r * SEQ + k0 + 64 + s * 16 + l16];
        }

        // S = Q K^T
        f32x4 sacc[4] = {};
#pragma unroll
        for (int ks = 0; ks < 2; ++ks)
#pragma unroll
            for (int s = 0; s < 4; ++s)
                sacc[s] = mfma16(qf[ks], kf[cur][ks][s], sacc[s]);

        // p = exp(s + bias); row-sum deferred to epilogue
#pragma unroll
        for (int r = 0; r < 4; ++r)
#pragma unroll
            for (int s = 0; s < 4; ++s) {
                const float p = __expf(sacc[s][r] + bv[cur][r][s]);
                lsum[r] += p;
                Ps[quad * 4 + r][s * 16 + l16] = f2bf(p);
            }
        asm volatile("" ::: "memory");   // order Ps writes before Ps reads (same wave)

        // O += P V
#pragma unroll
        for (int ks = 0; ks < 2; ++ks) {
            short8 pf = *(const short8*)&Ps[l16][ks * 32 + quad * 8];
#pragma unroll
            for (int s = 0; s < 4; ++s)
                oacc[s] = mfma16(pf, vf[cur][ks][s], oacc[s]);
        }
    }

    // epilogue: cross-lane row-sum, normalize, write attnb [4096][512]
#pragma unroll
    for (int r = 0; r < 4; ++r) {
        float rs = lsum[r];
        rs += __shfl_xor(rs, 1, 16);
        rs += __shfl_xor(rs, 2, 16);
        rs += __shfl_xor(rs, 4, 16);
        rs += __shfl_xor(rs, 8, 16);
        const float invl = 1.0f / rs;
        const size_t m = (size_t)b * SEQ + q0 + quad * 4 + r;
#pragma unroll
        for (int s = 0; s < 4; ++s)
            ob[m * 512 + h * HDIM + s * 16 + l16] = f2bf(oacc[s][r] * invl);
    }
}

// ------- out GEMM: single-wave 32x64 tile, LDS-free, barrier-free --------
__global__ __launch_bounds__(64)
void gemm_out(const ushort* __restrict__ Ab, const ushort* __restrict__ wT,
              float* __restrict__ C)
{
    const int lane = threadIdx.x, quad = lane >> 4, l16 = lane & 15;
    const int n0 = blockIdx.x * 64, m0 = blockIdx.y * 32;
    f32x4 acc[2][4] = {};

#pragma unroll 4
    for (int k0 = 0; k0 < 512; k0 += 32) {
        short8 a[2], bfr[4];
#pragma unroll
        for (int i = 0; i < 2; ++i)
            a[i] = *(const short8*)&Ab[(size_t)(m0 + i * 16 + l16) * 512 + k0 + quad * 8];
#pragma unroll
        for (int j = 0; j < 4; ++j)
            bfr[j] = *(const short8*)&wT[(size_t)(n0 + j * 16 + l16) * 512 + k0 + quad * 8];
#pragma unroll
        for (int i = 0; i < 2; ++i)
#pragma unroll
            for (int j = 0; j < 4; ++j)
                acc[i][j] = mfma16(a[i], bfr[j], acc[i][j]);
    }
#pragma unroll
    for (int i = 0; i < 2; ++i)
#pragma unroll
    for (int r = 0; r < 4; ++r) {
        const int m = m0 + i * 16 + quad * 4 + r;
#pragma unroll
        for (int j = 0; j < 4; ++j)
            C[(size_t)m * 512 + n0 + j * 16 + l16] = acc[i][j][r];
    }
}

extern "C" void kernel_launch(void* const* d_in, const int* in_sizes, int n_in,
                              void* d_out, int out_size, void* d_ws, size_t ws_size,
                              hipStream_t stream)
{
    const float* x        = (const float*)d_in[0];
    const float* pos_bias = (const float*)d_in[1];
    const float* w_qkv    = (const float*)d_in[2];
    const float* w_out    = (const float*)d_in[3];
    float* out = (float*)d_out;

    char* ws = (char*)d_ws;
    ushort* xb     = (ushort*)(ws);                            // 4 MB
    ushort* wqkvT  = (ushort*)(ws + 4194304);                  // 1.5 MB
    ushort* woutT  = (ushort*)(ws + 5767168);                  // 0.5 MB
    ushort* qb     = (ushort*)(ws + 6291456);                  // 4 MB
    ushort* kb     = (ushort*)(ws + 10485760);                 // 4 MB
    ushort* vtb    = (ushort*)(ws + 14680064);                 // 4 MB (V^T)
    ushort* attnb  = (ushort*)(ws + 18874368);                 // 4 MB

    prep<<<1280, 256, 0, stream>>>(x, w_qkv, w_out, xb, wqkvT, woutT);
    gemm_qkv_rope<<<dim3(24, 128), 64, 0, stream>>>(xb, wqkvT, qb, kb, vtb);
    flash_attn_wave<<<dim3(SEQ / 16, NHEAD, BATCH), 64, 0, stream>>>(qb, kb, vtb, pos_bias, attnb);
    gemm_out<<<dim3(8, 128), 64, 0, stream>>>(attnb, woutT, out);
}

// Round 8
// 257.192 us; speedup vs baseline: 1.3871x; 1.3871x over previous
//
#include <hip/hip_runtime.h>
#include <math.h>

#define SEQ 2048
#define NHEAD 8
#define HDIM 64
#define BATCH 2

typedef __attribute__((ext_vector_type(8))) short short8;
typedef __attribute__((ext_vector_type(4))) float f32x4;

__device__ __forceinline__ ushort f2bf(float f) {
    union { float f; unsigned u; } v; v.f = f;
    unsigned r = v.u + 0x7FFFu + ((v.u >> 16) & 1u);   // RNE
    return (ushort)(r >> 16);
}

__device__ __forceinline__ f32x4 mfma16(short8 a, short8 b, f32x4 c) {
    return __builtin_amdgcn_mfma_f32_16x16x32_bf16(a, b, c, 0, 0, 0);
}

// global->LDS DMA, 16B per lane; ldsp must be wave-uniform (lane i lands at
// ldsp + i*16).
__device__ __forceinline__ void gld16(const void* g, void* l) {
    __builtin_amdgcn_global_load_lds(
        (const __attribute__((address_space(1))) unsigned int*)g,
        (__attribute__((address_space(3))) unsigned int*)l, 16, 0, 0);
}

// ---------------- fused prep: pack x + transpose both weights ------------
__global__ __launch_bounds__(256)
void prep(const float* __restrict__ x, const float* __restrict__ w_qkv,
          const float* __restrict__ w_out, ushort* __restrict__ xb,
          ushort* __restrict__ wqkvT, ushort* __restrict__ woutT)
{
    __shared__ ushort tile[64][66];
    const int blk = blockIdx.x, t = threadIdx.x;
    if (blk < 1024) {                       // pack x -> bf16
        const int i = (blk * 256 + t) * 8;
        float4 a = *(const float4*)&x[i];
        float4 b = *(const float4*)&x[i + 4];
        union { ushort us[8]; uint4 v; } pk;
        pk.us[0] = f2bf(a.x); pk.us[1] = f2bf(a.y); pk.us[2] = f2bf(a.z); pk.us[3] = f2bf(a.w);
        pk.us[4] = f2bf(b.x); pk.us[5] = f2bf(b.y); pk.us[6] = f2bf(b.z); pk.us[7] = f2bf(b.w);
        *(uint4*)&xb[i] = pk.v;
        return;
    }
    const float* w; ushort* wT; int K, N, n0, k0;
    if (blk < 1216) { const int s = blk - 1024; w = w_qkv; wT = wqkvT; K = 512; N = 1536; n0 = (s % 24) * 64; k0 = (s / 24) * 64; }
    else            { const int s = blk - 1216; w = w_out; wT = woutT; K = 512; N = 512;  n0 = (s % 8) * 64;  k0 = (s / 8) * 64; }
#pragma unroll
    for (int i = 0; i < 4; ++i) {
        const int slot = t + i * 256;
        const int r = slot >> 4, c4 = (slot & 15) * 4;
        float4 v = *(const float4*)&w[(size_t)(k0 + r) * N + n0 + c4];
        tile[c4 + 0][r] = f2bf(v.x);
        tile[c4 + 1][r] = f2bf(v.y);
        tile[c4 + 2][r] = f2bf(v.z);
        tile[c4 + 3][r] = f2bf(v.w);
    }
    __syncthreads();
    const int n = t >> 2, kc = (t & 3) * 16;
    union { ushort us[16]; uint4 v[2]; } o;
#pragma unroll
    for (int j = 0; j < 16; ++j) o.us[j] = tile[n][kc + j];
    *(uint4*)&wT[(size_t)(n0 + n) * K + k0 + kc]     = o.v[0];
    *(uint4*)&wT[(size_t)(n0 + n) * K + k0 + kc + 8] = o.v[1];
}

// ---------- QKV GEMM 64x128, global_load_lds staging, + RoPE epilogue ----
__global__ __launch_bounds__(256)
void gemm_qkv_rope(const ushort* __restrict__ xb, const ushort* __restrict__ wT,
                   ushort* __restrict__ qb, ushort* __restrict__ kb,
                   ushort* __restrict__ vtb)
{
    __shared__ __align__(16) ushort As[64][64];    // unpadded: DMA target
    __shared__ __align__(16) ushort Bs[128][64];
    const int t = threadIdx.x, lane = t & 63, w = t >> 6;
    const int quad = lane >> 4, l16 = lane & 15;
    const int m0 = blockIdx.y * 64, n0 = blockIdx.x * 128;
    const int mw = (w >> 1) * 32, nw = (w & 1) * 64;
    const int krow = lane >> 3, kcol = (lane & 7) * 8;   // DMA lane mapping
    f32x4 acc[2][4] = {};

    for (int k0 = 0; k0 < 512; k0 += 64) {
        __syncthreads();   // previous tile's readers done
        gld16(&xb[(size_t)(m0 + w * 8 + krow) * 512 + k0 + kcol],        &As[w * 8][0]);
        gld16(&xb[(size_t)(m0 + (w + 4) * 8 + krow) * 512 + k0 + kcol],  &As[(w + 4) * 8][0]);
#pragma unroll
        for (int jj = 0; jj < 4; ++jj) {
            const int j = w * 4 + jj;
            gld16(&wT[(size_t)(n0 + j * 8 + krow) * 512 + k0 + kcol], &Bs[j * 8][0]);
        }
        __syncthreads();   // vmcnt drained -> tiles ready
#pragma unroll
        for (int ks = 0; ks < 2; ++ks) {
            short8 a[2], b[4];
#pragma unroll
            for (int i = 0; i < 2; ++i)
                a[i] = *(const short8*)&As[mw + i * 16 + l16][ks * 32 + quad * 8];
#pragma unroll
            for (int j = 0; j < 4; ++j)
                b[j] = *(const short8*)&Bs[nw + j * 16 + l16][ks * 32 + quad * 8];
#pragma unroll
            for (int i = 0; i < 2; ++i)
#pragma unroll
                for (int j = 0; j < 4; ++j)
                    acc[i][j] = mfma16(a[i], b[j], acc[i][j]);
        }
    }

    const int sec = (n0 + nw) >> 9;   // 0=q 1=k 2=v, wave-uniform
    if (sec == 2) {
#pragma unroll
        for (int i = 0; i < 2; ++i) {
            const int m = m0 + mw + i * 16 + quad * 4;
            const int bidx = m >> 11, n = m & 2047;
#pragma unroll
            for (int j = 0; j < 4; ++j) {
                const int nc = n0 + nw + j * 16 + l16;
                const int d = nc & 63, h = (nc >> 6) & 7;
                ushort4 pk;
                pk.x = f2bf(acc[i][j][0]); pk.y = f2bf(acc[i][j][1]);
                pk.z = f2bf(acc[i][j][2]); pk.w = f2bf(acc[i][j][3]);
                *(ushort4*)&vtb[(((size_t)bidx * 8 + h) * 64 + d) * 2048 + n] = pk;
            }
        }
    } else {
        ushort* dst = (sec == 0) ? qb : kb;
        const float scale = (sec == 0) ? 0.125f : 1.0f;
#pragma unroll
        for (int j = 0; j < 4; ++j) {
            const int nc = n0 + nw + j * 16 + l16;
            const int d = nc & 63, h = (nc >> 6) & 7;
            const float inv = __expf(-(float)(d & ~1) * (9.2103403719761836f / 64.0f));
#pragma unroll
            for (int i = 0; i < 2; ++i)
#pragma unroll
            for (int r = 0; r < 4; ++r) {
                const int m = m0 + mw + i * 16 + quad * 4 + r;
                const int bidx = m >> 11, n = m & 2047;
                float sn, cs;
                __sincosf((float)n * inv, &sn, &cs);
                const float vacc = acc[i][j][r];
                const float partner = __shfl_xor(vacc, 1);
                const float rot = (d & 1) ? (vacc * cs + partner * sn)
                                          : (vacc * cs - partner * sn);
                dst[(((size_t)bidx * 8 + h) * 2048 + n) * 64 + d] = f2bf(rot * scale);
            }
        }
    }
}

// ---------- flash attention: K/V/bias via global_load_lds, 2-barrier -----
__global__ __launch_bounds__(256)
void flash_attn_mfma(const ushort* __restrict__ qb, const ushort* __restrict__ kb,
                     const ushort* __restrict__ vtb, const float* __restrict__ bias,
                     ushort* __restrict__ ob)
{
    __shared__ __align__(16) ushort Ks[64][64];   // unpadded: DMA targets
    __shared__ __align__(16) ushort Vt[64][64];   // [dim][seqpos]
    __shared__ __align__(16) float  Bl[64][64];   // bias tile fp32
    __shared__ __align__(16) ushort Ps[4][16][72];
    const int t = threadIdx.x, lane = t & 63, w = t >> 6;
    const int quad = lane >> 4, l16 = lane & 15;
    const int q0 = blockIdx.x * 64, h = blockIdx.y, b = blockIdx.z;
    const size_t bh = (size_t)(b * NHEAD + h);
    const ushort* Q  = qb  + bh * SEQ * HDIM;
    const ushort* Kp = kb  + bh * SEQ * HDIM;
    const ushort* VT = vtb + bh * HDIM * SEQ;

    short8 qf[2];
    qf[0] = *(const short8*)&Q[(size_t)(q0 + w * 16 + l16) * HDIM + quad * 8];
    qf[1] = *(const short8*)&Q[(size_t)(q0 + w * 16 + l16) * HDIM + 32 + quad * 8];

    f32x4 oacc[4] = {};
    float lsum[4] = {};
    const int krow = lane >> 3, kcol = (lane & 7) * 8;   // K/V DMA mapping
    const int brow = lane >> 4, bcol = (lane & 15) * 4;  // bias DMA mapping

    for (int it = 0; it < 32; ++it) {
        const int k0 = it * 64;
        __syncthreads();   // previous tile's readers done
        gld16(&Kp[(size_t)(k0 + w * 8 + krow) * HDIM + kcol],       &Ks[w * 8][0]);
        gld16(&Kp[(size_t)(k0 + (w + 4) * 8 + krow) * HDIM + kcol], &Ks[(w + 4) * 8][0]);
        gld16(&VT[(size_t)(w * 8 + krow) * SEQ + k0 + kcol],        &Vt[w * 8][0]);
        gld16(&VT[(size_t)((w + 4) * 8 + krow) * SEQ + k0 + kcol],  &Vt[(w + 4) * 8][0]);
#pragma unroll
        for (int jj = 0; jj < 4; ++jj) {
            const int j = w * 4 + jj;
            gld16(&bias[((size_t)h * SEQ + q0 + j * 4 + brow) * SEQ + k0 + bcol], &Bl[j * 4][0]);
        }
        __syncthreads();   // vmcnt drained -> tiles ready

        // S = Q K^T
        f32x4 sacc[4] = {};
#pragma unroll
        for (int ks = 0; ks < 2; ++ks)
#pragma unroll
            for (int s = 0; s < 4; ++s) {
                short8 kf = *(const short8*)&Ks[s * 16 + l16][ks * 32 + quad * 8];
                sacc[s] = mfma16(qf[ks], kf, sacc[s]);
            }

        // p = exp(s + bias); row-sum deferred to epilogue
        // NOTE: bias row must include this wave's q-row offset (w*16)!
#pragma unroll
        for (int r = 0; r < 4; ++r)
#pragma unroll
            for (int s = 0; s < 4; ++s) {
                const float p = __expf(sacc[s][r] + Bl[w * 16 + quad * 4 + r][s * 16 + l16]);
                lsum[r] += p;
                Ps[w][quad * 4 + r][s * 16 + l16] = f2bf(p);
            }
        asm volatile("" ::: "memory");   // per-wave Ps: order writes before reads

        // O += P V
#pragma unroll
        for (int ks = 0; ks < 2; ++ks) {
            short8 pf = *(const short8*)&Ps[w][l16][ks * 32 + quad * 8];
#pragma unroll
            for (int s = 0; s < 4; ++s) {
                short8 vf = *(const short8*)&Vt[s * 16 + l16][ks * 32 + quad * 8];
                oacc[s] = mfma16(pf, vf, oacc[s]);
            }
        }
    }

    // epilogue: cross-lane row-sum, normalize, write attnb [4096][512]
#pragma unroll
    for (int r = 0; r < 4; ++r) {
        float rs = lsum[r];
        rs += __shfl_xor(rs, 1, 16);
        rs += __shfl_xor(rs, 2, 16);
        rs += __shfl_xor(rs, 4, 16);
        rs += __shfl_xor(rs, 8, 16);
        const float invl = 1.0f / rs;
        const size_t m = (size_t)b * SEQ + q0 + w * 16 + quad * 4 + r;
#pragma unroll
        for (int s = 0; s < 4; ++s)
            ob[m * 512 + h * HDIM + s * 16 + l16] = f2bf(oacc[s][r] * invl);
    }
}

// ---------- out GEMM 64x64, global_load_lds staging ----------------------
__global__ __launch_bounds__(256)
void gemm_out(const ushort* __restrict__ Ab, const ushort* __restrict__ wT,
              float* __restrict__ C)
{
    __shared__ __align__(16) ushort As[64][64];
    __shared__ __align__(16) ushort Bs[64][64];
    const int t = threadIdx.x, lane = t & 63, w = t >> 6;
    const int quad = lane >> 4, l16 = lane & 15;
    const int m0 = blockIdx.y * 64, n0 = blockIdx.x * 64;
    const int mw = (w >> 1) * 32, nw = (w & 1) * 32;
    const int krow = lane >> 3, kcol = (lane & 7) * 8;
    f32x4 acc[2][2] = {};

    for (int k0 = 0; k0 < 512; k0 += 64) {
        __syncthreads();
        gld16(&Ab[(size_t)(m0 + w * 8 + krow) * 512 + k0 + kcol],       &As[w * 8][0]);
        gld16(&Ab[(size_t)(m0 + (w + 4) * 8 + krow) * 512 + k0 + kcol], &As[(w + 4) * 8][0]);
        gld16(&wT[(size_t)(n0 + w * 8 + krow) * 512 + k0 + kcol],       &Bs[w * 8][0]);
        gld16(&wT[(size_t)(n0 + (w + 4) * 8 + krow) * 512 + k0 + kcol], &Bs[(w + 4) * 8][0]);
        __syncthreads();
#pragma unroll
        for (int ks = 0; ks < 2; ++ks) {
            short8 a[2], b[2];
#pragma unroll
            for (int i = 0; i < 2; ++i)
                a[i] = *(const short8*)&As[mw + i * 16 + l16][ks * 32 + quad * 8];
#pragma unroll
            for (int j = 0; j < 2; ++j)
                b[j] = *(const short8*)&Bs[nw + j * 16 + l16][ks * 32 + quad * 8];
#pragma unroll
            for (int i = 0; i < 2; ++i)
#pragma unroll
                for (int j = 0; j < 2; ++j)
                    acc[i][j] = mfma16(a[i], b[j], acc[i][j]);
        }
    }
#pragma unroll
    for (int i = 0; i < 2; ++i)
#pragma unroll
    for (int r = 0; r < 4; ++r) {
        const int m = m0 + mw + i * 16 + quad * 4 + r;
#pragma unroll
        for (int j = 0; j < 2; ++j)
            C[(size_t)m * 512 + n0 + nw + j * 16 + l16] = acc[i][j][r];
    }
}

extern "C" void kernel_launch(void* const* d_in, const int* in_sizes, int n_in,
                              void* d_out, int out_size, void* d_ws, size_t ws_size,
                              hipStream_t stream)
{
    const float* x        = (const float*)d_in[0];
    const float* pos_bias = (const float*)d_in[1];
    const float* w_qkv    = (const float*)d_in[2];
    const float* w_out    = (const float*)d_in[3];
    float* out = (float*)d_out;

    char* ws = (char*)d_ws;
    ushort* xb     = (ushort*)(ws);                            // 4 MB
    ushort* wqkvT  = (ushort*)(ws + 4194304);                  // 1.5 MB
    ushort* woutT  = (ushort*)(ws + 5767168);                  // 0.5 MB
    ushort* qb     = (ushort*)(ws + 6291456);                  // 4 MB
    ushort* kb     = (ushort*)(ws + 10485760);                 // 4 MB
    ushort* vtb    = (ushort*)(ws + 14680064);                 // 4 MB (V^T)
    ushort* attnb  = (ushort*)(ws + 18874368);                 // 4 MB

    prep<<<1280, 256, 0, stream>>>(x, w_qkv, w_out, xb, wqkvT, woutT);
    gemm_qkv_rope<<<dim3(12, 64), 256, 0, stream>>>(xb, wqkvT, qb, kb, vtb);
    flash_attn_mfma<<<dim3(SEQ / 64, NHEAD, BATCH), 256, 0, stream>>>(qb, kb, vtb, pos_bias, attnb);
    gemm_out<<<dim3(8, 64), 256, 0, stream>>>(attnb, woutT, out);
}